// Round 5
// baseline (1218.972 us; speedup 1.0000x reference)
//
#include <hip/hip_runtime.h>
#include <math.h>

namespace {

constexpr int Hn = 50;    // hidden size
constexpr int Bn = 2048;  // batch
constexpr int Tn = 512;   // sequence length
constexpr int SW = 72;    // plane row stride in shorts (144 B: 16B-slot stride 16 mod 128 -> 2-way = free)

constexpr float KS1f = -1.44269504088896340736f;  // -log2(e)   (sigmoid rows i,f,o)
constexpr float KS2f = -2.88539008177792681472f;  // -2*log2(e) (tanh row g, and tanh(c))

typedef short short8 __attribute__((ext_vector_type(8)));
typedef float f32x4 __attribute__((ext_vector_type(4)));

__device__ __forceinline__ unsigned bcu(float f) { return __builtin_bit_cast(unsigned, f); }
__device__ __forceinline__ float bcf(unsigned u) { return __builtin_bit_cast(float, u); }
__device__ __forceinline__ float rcpa(float x) { return __builtin_amdgcn_rcpf(x); }

// 2^x. Guarded: __builtin_amdgcn_exp2f is the direct v_exp_f32 path; if this
// toolchain doesn't have it, exp2f() (OCML) lowers to v_exp_f32 + fixups.
__device__ __forceinline__ float fexp2(float x) {
#if defined(__has_builtin)
#if __has_builtin(__builtin_amdgcn_exp2f)
  return __builtin_amdgcn_exp2f(x);
#else
  return exp2f(x);
#endif
#else
  return exp2f(x);
#endif
}

__device__ __forceinline__ void wsplit(short* ph, short* pl, float v) {
  const unsigned u = bcu(v);
  *ph = (short)(u >> 16);
  *pl = (short)(bcu(v - bcf(u & 0xFFFF0000u)) >> 16);
}

#define MF(a, b, c) __builtin_amdgcn_mfma_f32_16x16x32_bf16(a, b, c, 0, 0, 0)

// ============================================================================
// FUSED 3-layer LSTM + FC, systolic in time. 128 blocks x 512 thr (8 waves =
// l1:2, l2:3, l3:3), 16 elems/block, ONE barrier/iter.
// R12 changes (attack in-order-issue stalls; spills already dead per R11):
//  - TERM-MAJOR MFMA ordering: per chunk emit pass A = FH*uh for ALL tiles,
//    then pass B = FL*uh, then pass C = FH*ul. R11's tile-major order put 3
//    back-to-back DEPENDENT MFMAs (same acc) in program order -> in-order
//    wave issue stalled ~2x MFMA latency per tile (~600 cy/iter/wave).
//    Now dependent ops on one acc are 5-7 independent MFMAs apart.
//    Per-acc accumulation order is unchanged (A,B,C per chunk) -> bit-same.
//  - biases back in REGISTERS (R9 moved them to LDS out of VGPR fear; R11
//    freed 64 VGPRs via s_f4, so bv regs fit: ~150 < 256 cap). Removes
//    5-7 ds_read_b128 per wave-iter from the CU-shared LDS pipe.
// R11 (kept): tile J=4 fragments in LDS (s_f4), read per chunk (MTMS passes).
// R9/R10 (kept): __launch_bounds__(512,1); exp2-prescaled weights/biases
// (sigmoid rows * -log2e, tanh rows * -2log2e) -> gates are rcp(1+exp2(z'));
// tanh = 2*rcp(1+e)-1; guarded fexp2.
// fp32 accuracy via 3-term split-bf16 (Wh*Uh + Wl*Uh + Wh*Ul); planes K=64:
// P1=[x,h1(1..50)], P2=[h2], P3=[h3]; l2 consumes {P1,P2}, l3 {P2,P3}.
// ============================================================================

#define LW(FI)                                                               \
  short8 FH##FI = {0, 0, 0, 0, 0, 0, 0, 0};                                  \
  short8 FL##FI = {0, 0, 0, 0, 0, 0, 0, 0};                                  \
  {                                                                          \
    const int tile_ = (L == 0) ? (wl + 2 * ((FI) >> 1))                      \
                               : (wl + 3 * ((FI) >> 2));                     \
    const int chunk_ = (L == 0) ? ((FI)&1) : ((FI)&3);                       \
    const int cb_ = 4 * tile_ + (nl >> 2);                                   \
    if (tile_ < 13 && cb_ < Hn) {                                            \
      const int row_ = (nl & 3) * Hn + cb_;                                  \
      const float sc_ = ((nl & 3) == 2) ? KS2f : KS1f;                       \
      _Pragma("unroll") for (int jj = 0; jj < 8; ++jj) {                     \
        const int k_ = 32 * chunk_ + quad * 8 + jj;                          \
        float wv = 0.f;                                                      \
        if (L == 0) {                                                        \
          if (k_ == 0) wv = wihL[row_];                                      \
          else if (k_ <= Hn) wv = whhL[row_ * Hn + k_ - 1];                  \
        } else if (L == 1) {                                                 \
          if (k_ >= 1 && k_ <= Hn) wv = wihL[row_ * Hn + k_ - 1];            \
          else if (k_ >= 64 && k_ < 64 + Hn) wv = whhL[row_ * Hn + k_ - 64]; \
        } else {                                                             \
          if (k_ < Hn) wv = wihL[row_ * Hn + k_];                            \
          else if (k_ >= 64 && k_ < 64 + Hn) wv = whhL[row_ * Hn + k_ - 64]; \
        }                                                                    \
        wv *= sc_;                                                           \
        const unsigned uu = bcu(wv);                                         \
        FH##FI[jj] = (short)(uu >> 16);                                      \
        FL##FI[jj] = (short)(bcu(wv - bcf(uu & 0xFFFF0000u)) >> 16);         \
      }                                                                      \
    }                                                                        \
  }

// bias in REGISTERS, prescaled (rows i,f,o by KS1f; row g by KS2f)
#define BINIT(J)                                                             \
  const int tile##J =                                                        \
      (L == 0) ? (wl + 2 * (J)) : ((J) < 5 ? (wl + 3 * (J)) : 13);           \
  const int tv##J = tile##J < 13;                                            \
  const int cell##J = 4 * tile##J + quad;                                    \
  f32x4 bv##J = {0.f, 0.f, 0.f, 0.f};                                        \
  if (tv##J && cell##J < Hn) {                                               \
    bv##J[0] = biasL[cell##J] * KS1f;                                        \
    bv##J[1] = biasL[Hn + cell##J] * KS1f;                                   \
    bv##J[2] = biasL[2 * Hn + cell##J] * KS2f;                               \
    bv##J[3] = biasL[3 * Hn + cell##J] * KS1f;                               \
  }                                                                          \
  float cs##J = 0.f, hl##J = 0.f;

// term-major passes: A = FH*uh, B = FL*uh, C = FH*ul
#define MFA(J, FI) if (tv##J) ac##J = MF(FH##FI, uh_, ac##J);
#define MFB(J, FI) if (tv##J) ac##J = MF(FL##FI, uh_, ac##J);
#define MFC(J, FI) if (tv##J) ac##J = MF(FH##FI, ul_, ac##J);

// LC = chunk offset within the source plane (0 or 1); CI = combined chunk idx
// tile J=4's fragments come from LDS (only waves wl==0 of L1/L2 have tv4)
#define MCH5(PH, PL, LC, CI, F0, F1, F2, F3)                                 \
  {                                                                          \
    const short8 uh_ = *(const short8*)&PH[rb][nl][32 * (LC) + quad * 8];    \
    const short8 ul_ = *(const short8*)&PL[rb][nl][32 * (LC) + quad * 8];    \
    short8 f4h_ = {0, 0, 0, 0, 0, 0, 0, 0};                                  \
    short8 f4l_ = {0, 0, 0, 0, 0, 0, 0, 0};                                  \
    if (tv4) {                                                               \
      f4h_ = s_f4[wz2][CI][0][lane];                                         \
      f4l_ = s_f4[wz2][CI][1][lane];                                         \
    }                                                                        \
    MFA(0, F0) MFA(1, F1) MFA(2, F2) MFA(3, F3)                              \
    if (tv4) ac4 = MF(f4h_, uh_, ac4);                                       \
    MFB(0, F0) MFB(1, F1) MFB(2, F2) MFB(3, F3)                              \
    if (tv4) ac4 = MF(f4l_, uh_, ac4);                                       \
    MFC(0, F0) MFC(1, F1) MFC(2, F2) MFC(3, F3)                              \
    if (tv4) ac4 = MF(f4h_, ul_, ac4);                                       \
  }

#define MCH7(LC, F0, F1, F2, F3, F4, F5, F6)                                 \
  {                                                                          \
    const short8 uh_ = *(const short8*)&p1h[rb][nl][32 * (LC) + quad * 8];   \
    const short8 ul_ = *(const short8*)&p1l[rb][nl][32 * (LC) + quad * 8];   \
    MFA(0, F0) MFA(1, F1) MFA(2, F2) MFA(3, F3) MFA(4, F4) MFA(5, F5)        \
    MFA(6, F6)                                                               \
    MFB(0, F0) MFB(1, F1) MFB(2, F2) MFB(3, F3) MFB(4, F4) MFB(5, F5)        \
    MFB(6, F6)                                                               \
    MFC(0, F0) MFC(1, F1) MFC(2, F2) MFC(3, F3) MFC(4, F4) MFC(5, F5)        \
    MFC(6, F6)                                                               \
  }

// cell update for tile J; SINGLE h write into plane (PH,PL) at k = KO+cell
// gates arrive pre-scaled: sigmoid = rcp(1+exp2(z')), tanh = 2*rcp(1+e)-1
#define CUP(J, PH, PL, KO)                                                   \
  if (tv##J) {                                                               \
    const float I_ = rcpa(1.0f + fexp2(ac##J[0]));                           \
    const float F_ = rcpa(1.0f + fexp2(ac##J[1]));                           \
    const float G_ = fmaf(2.0f, rcpa(1.0f + fexp2(ac##J[2])), -1.0f);        \
    const float O_ = rcpa(1.0f + fexp2(ac##J[3]));                           \
    cs##J = fmaf(F_, cs##J, I_ * G_);                                        \
    const float tc_ = fmaf(2.0f, rcpa(1.0f + fexp2(cs##J * KS2f)), -1.0f);   \
    const float hv = O_ * tc_;                                               \
    hl##J = hv;                                                              \
    if (cell##J < Hn)                                                        \
      wsplit(&PH[wb][nl][(KO) + cell##J], &PL[wb][nl][(KO) + cell##J], hv);  \
  }

__global__ __launch_bounds__(512, 1) void lstm_fused(
    const float* __restrict__ xg,    // [B][T]
    const float* __restrict__ wih1, const float* __restrict__ whh1,
    const float* __restrict__ b1, const float* __restrict__ wih2,
    const float* __restrict__ whh2, const float* __restrict__ b2,
    const float* __restrict__ wih3, const float* __restrict__ whh3,
    const float* __restrict__ b3, const float* __restrict__ wfc,
    const float* __restrict__ bfc, float* __restrict__ out)  // [B]
{
  __shared__ __align__(16) short p1h[2][16][SW];  // [x | h1(1..50)]
  __shared__ __align__(16) short p1l[2][16][SW];
  __shared__ __align__(16) short p2h[2][16][SW];  // [h2(0..49)]
  __shared__ __align__(16) short p2l[2][16][SW];
  __shared__ __align__(16) short p3h[2][16][SW];  // [h3(0..49)]
  __shared__ __align__(16) short p3l[2][16][SW];
  __shared__ __align__(16) short8 s_f4[2][4][2][64];  // tile-4 frags: [L-1][chunk][H/L][lane]
  __shared__ float s_fc[3][16];

  const int tid = threadIdx.x;
  const int w = tid >> 6;
  const int lane = tid & 63;
  const int quad = lane >> 4;
  const int nl = lane & 15;
  const int L = (w < 2) ? 0 : (w < 5) ? 1 : 2;
  const int wl = w - (L == 0 ? 0 : (L == 1 ? 2 : 5));
  const int wz2 = (L == 2) ? 1 : 0;
  const int eb = blockIdx.x * 16;

  const float* wihL = (L == 0) ? wih1 : (L == 1) ? wih2 : wih3;
  const float* whhL = (L == 0) ? whh1 : (L == 1) ? whh2 : whh3;
  const float* biasL = (L == 0) ? b1 : (L == 1) ? b2 : b3;

  LW(0) LW(1) LW(2) LW(3) LW(4) LW(5) LW(6) LW(7) LW(8) LW(9)
  LW(10) LW(11) LW(12) LW(13) LW(14) LW(15) LW(16) LW(17) LW(18) LW(19)

  // park tile-4 fragments in LDS; their registers die here (read in MCH5)
  if (L > 0 && wl == 0) {
    s_f4[wz2][0][0][lane] = FH16; s_f4[wz2][0][1][lane] = FL16;
    s_f4[wz2][1][0][lane] = FH17; s_f4[wz2][1][1][lane] = FL17;
    s_f4[wz2][2][0][lane] = FH18; s_f4[wz2][2][1][lane] = FL18;
    s_f4[wz2][3][0][lane] = FH19; s_f4[wz2][3][1][lane] = FL19;
  }

  BINIT(0) BINIT(1) BINIT(2) BINIT(3) BINIT(4) BINIT(5) BINIT(6)

  for (int i = tid; i < 2 * 16 * SW; i += 512) {
    (&p1h[0][0][0])[i] = 0;
    (&p1l[0][0][0])[i] = 0;
    (&p2h[0][0][0])[i] = 0;
    (&p2l[0][0][0])[i] = 0;
    (&p3h[0][0][0])[i] = 0;
    (&p3l[0][0][0])[i] = 0;
  }
  __syncthreads();
  if (w == 0 && lane < 16) {
    const float xv = xg[(size_t)(eb + lane) * Tn + 0];
    wsplit(&p1h[0][lane][0], &p1l[0][lane][0], xv);
  }
  __syncthreads();

#pragma unroll 1
  for (int i = 0; i < Tn + 2; ++i) {
    const int rb = i & 1, wb = rb ^ 1;
    if (L == 0) {
      if (i < Tn) {
        float xv = 0.f;
        if (w == 0 && lane < 16 && i + 1 < Tn)
          xv = xg[(size_t)(eb + lane) * Tn + (i + 1)];
        f32x4 ac0 = bv0, ac1 = bv1, ac2 = bv2, ac3 = bv3, ac4 = bv4,
              ac5 = bv5, ac6 = bv6;
        MCH7(0, 0, 2, 4, 6, 8, 10, 12)
        MCH7(1, 1, 3, 5, 7, 9, 11, 13)
        CUP(0, p1h, p1l, 1)
        CUP(1, p1h, p1l, 1)
        CUP(2, p1h, p1l, 1)
        CUP(3, p1h, p1l, 1)
        CUP(4, p1h, p1l, 1)
        CUP(5, p1h, p1l, 1)
        CUP(6, p1h, p1l, 1)
        if (w == 0 && lane < 16)
          wsplit(&p1h[wb][lane][0], &p1l[wb][lane][0], xv);
      }
    } else if (L == 1) {
      if (i >= 1 && i <= Tn) {
        f32x4 ac0 = bv0, ac1 = bv1, ac2 = bv2, ac3 = bv3, ac4 = bv4;
        MCH5(p1h, p1l, 0, 0, 0, 4, 8, 12)    // combined k 0..31  (h1)
        MCH5(p1h, p1l, 1, 1, 1, 5, 9, 13)    // combined k 32..63 (h1)
        MCH5(p2h, p2l, 0, 2, 2, 6, 10, 14)   // combined k 64..95 (h2)
        MCH5(p2h, p2l, 1, 3, 3, 7, 11, 15)   // combined k 96..127(h2)
        CUP(0, p2h, p2l, 0)
        CUP(1, p2h, p2l, 0)
        CUP(2, p2h, p2l, 0)
        CUP(3, p2h, p2l, 0)
        CUP(4, p2h, p2l, 0)
      }
    } else {
      if (i >= 2) {
        f32x4 ac0 = bv0, ac1 = bv1, ac2 = bv2, ac3 = bv3, ac4 = bv4;
        MCH5(p2h, p2l, 0, 0, 0, 4, 8, 12)    // h2
        MCH5(p2h, p2l, 1, 1, 1, 5, 9, 13)
        MCH5(p3h, p3l, 0, 2, 2, 6, 10, 14)   // h3
        MCH5(p3h, p3l, 1, 3, 3, 7, 11, 15)
        CUP(0, p3h, p3l, 0)
        CUP(1, p3h, p3l, 0)
        CUP(2, p3h, p3l, 0)
        CUP(3, p3h, p3l, 0)
        CUP(4, p3h, p3l, 0)
      }
    }
    __syncthreads();
  }

  if (L == 2) {
    float pfc = 0.f;
    if (tv0 && cell0 < Hn) pfc += hl0 * wfc[cell0];
    if (tv1 && cell1 < Hn) pfc += hl1 * wfc[cell1];
    if (tv2 && cell2 < Hn) pfc += hl2 * wfc[cell2];
    if (tv3 && cell3 < Hn) pfc += hl3 * wfc[cell3];
    if (tv4 && cell4 < Hn) pfc += hl4 * wfc[cell4];
    pfc += __shfl_xor(pfc, 16);  // sum over quads (cells)
    pfc += __shfl_xor(pfc, 32);
    if (lane < 16) s_fc[wl][lane] = pfc;
  }
  __syncthreads();
  if (tid < 16)
    out[eb + tid] = bfc[0] + s_fc[0][tid] + s_fc[1][tid] + s_fc[2][tid];
}

}  // namespace

extern "C" void kernel_launch(void* const* d_in, const int* in_sizes, int n_in,
                              void* d_out, int out_size, void* d_ws, size_t ws_size,
                              hipStream_t stream) {
  const float* x    = (const float*)d_in[0];
  const float* wih1 = (const float*)d_in[1];
  const float* whh1 = (const float*)d_in[2];
  const float* b1   = (const float*)d_in[3];
  const float* wih2 = (const float*)d_in[4];
  const float* whh2 = (const float*)d_in[5];
  const float* b2   = (const float*)d_in[6];
  const float* wih3 = (const float*)d_in[7];
  const float* whh3 = (const float*)d_in[8];
  const float* b3   = (const float*)d_in[9];
  const float* wfc  = (const float*)d_in[10];
  const float* bfc  = (const float*)d_in[11];
  float* out = (float*)d_out;

  lstm_fused<<<dim3(Bn / 16), dim3(512), 0, stream>>>(
      x, wih1, whh1, b1, wih2, whh2, b2, wih3, whh3, b3, wfc, bfc, out);
}

// Round 6
// 1163.802 us; speedup vs baseline: 1.0474x; 1.0474x over previous
//
#include <hip/hip_runtime.h>
#include <math.h>

namespace {

constexpr int Hn = 50;    // hidden size
constexpr int Bn = 2048;  // batch
constexpr int Tn = 512;   // sequence length
constexpr int SW = 72;    // plane row stride in shorts (144 B: 16B-slot stride 16 mod 128 -> 2-way = free)

constexpr float KS1f = -1.44269504088896340736f;  // -log2(e)   (sigmoid rows i,f,o)
constexpr float KS2f = -2.88539008177792681472f;  // -2*log2(e) (tanh row g, and tanh(c))

typedef short short8 __attribute__((ext_vector_type(8)));
typedef float f32x4 __attribute__((ext_vector_type(4)));

__device__ __forceinline__ unsigned bcu(float f) { return __builtin_bit_cast(unsigned, f); }
__device__ __forceinline__ float bcf(unsigned u) { return __builtin_bit_cast(float, u); }
__device__ __forceinline__ float rcpa(float x) { return __builtin_amdgcn_rcpf(x); }

// 2^x. Guarded: __builtin_amdgcn_exp2f is the direct v_exp_f32 path; if this
// toolchain doesn't have it, exp2f() (OCML) lowers to v_exp_f32 + fixups.
__device__ __forceinline__ float fexp2(float x) {
#if defined(__has_builtin)
#if __has_builtin(__builtin_amdgcn_exp2f)
  return __builtin_amdgcn_exp2f(x);
#else
  return exp2f(x);
#endif
#else
  return exp2f(x);
#endif
}

__device__ __forceinline__ void wsplit(short* ph, short* pl, float v) {
  const unsigned u = bcu(v);
  *ph = (short)(u >> 16);
  *pl = (short)(bcu(v - bcf(u & 0xFFFF0000u)) >> 16);
}

#define MF(a, b, c) __builtin_amdgcn_mfma_f32_16x16x32_bf16(a, b, c, 0, 0, 0)

// ============================================================================
// FUSED 3-layer LSTM + FC, systolic in time. 128 blocks x 512 thr (8 waves =
// l1:2, l2:3, l3:3), 16 elems/block, ONE barrier/iter.
// R13 = R11's register budget + R12's issue order (clean A/B of term-major):
//  - R12 regressed (951 -> 1235): bias-in-regs added 28 VGPRs, re-tipping
//    the allocator over the cliff (WRITE_SIZE 8 KB -> 1288 KB of spills).
//    This kernel sits AT the register cliff; nothing may add live state.
//  - So: biases back in LDS (s_bv, R11-proven zero-spill, VGPR=120), and
//    KEEP term-major MFMA ordering (register-neutral): per chunk emit
//    pass A = FH*uh for all tiles, then B = FL*uh, then C = FH*ul.
//    Dependent writes to one acc are now 5-7 independent MFMAs apart
//    instead of back-to-back (in-order issue stalled ~2x MFMA latency
//    per tile in tile-major order). Per-acc accumulation order unchanged.
// R11 (kept): tile J=4 fragments in LDS (s_f4), read once per chunk.
// R9/R10 (kept): __launch_bounds__(512,1); exp2-prescaled weights/biases
// (sigmoid rows * -log2e, tanh rows * -2log2e) -> gates are rcp(1+exp2(z'));
// tanh = 2*rcp(1+e)-1; guarded fexp2.
// fp32 accuracy via 3-term split-bf16 (Wh*Uh + Wl*Uh + Wh*Ul); planes K=64:
// P1=[x,h1(1..50)], P2=[h2], P3=[h3]; l2 consumes {P1,P2}, l3 {P2,P3}.
// ============================================================================

#define LW(FI)                                                               \
  short8 FH##FI = {0, 0, 0, 0, 0, 0, 0, 0};                                  \
  short8 FL##FI = {0, 0, 0, 0, 0, 0, 0, 0};                                  \
  {                                                                          \
    const int tile_ = (L == 0) ? (wl + 2 * ((FI) >> 1))                      \
                               : (wl + 3 * ((FI) >> 2));                     \
    const int chunk_ = (L == 0) ? ((FI)&1) : ((FI)&3);                       \
    const int cb_ = 4 * tile_ + (nl >> 2);                                   \
    if (tile_ < 13 && cb_ < Hn) {                                            \
      const int row_ = (nl & 3) * Hn + cb_;                                  \
      const float sc_ = ((nl & 3) == 2) ? KS2f : KS1f;                       \
      _Pragma("unroll") for (int jj = 0; jj < 8; ++jj) {                     \
        const int k_ = 32 * chunk_ + quad * 8 + jj;                          \
        float wv = 0.f;                                                      \
        if (L == 0) {                                                        \
          if (k_ == 0) wv = wihL[row_];                                      \
          else if (k_ <= Hn) wv = whhL[row_ * Hn + k_ - 1];                  \
        } else if (L == 1) {                                                 \
          if (k_ >= 1 && k_ <= Hn) wv = wihL[row_ * Hn + k_ - 1];            \
          else if (k_ >= 64 && k_ < 64 + Hn) wv = whhL[row_ * Hn + k_ - 64]; \
        } else {                                                             \
          if (k_ < Hn) wv = wihL[row_ * Hn + k_];                            \
          else if (k_ >= 64 && k_ < 64 + Hn) wv = whhL[row_ * Hn + k_ - 64]; \
        }                                                                    \
        wv *= sc_;                                                           \
        const unsigned uu = bcu(wv);                                         \
        FH##FI[jj] = (short)(uu >> 16);                                      \
        FL##FI[jj] = (short)(bcu(wv - bcf(uu & 0xFFFF0000u)) >> 16);         \
      }                                                                      \
    }                                                                        \
  }

#define BINIT(J)                                                             \
  const int tile##J =                                                        \
      (L == 0) ? (wl + 2 * (J)) : ((J) < 5 ? (wl + 3 * (J)) : 13);           \
  const int tv##J = tile##J < 13;                                            \
  const int cell##J = 4 * tile##J + quad;                                    \
  float cs##J = 0.f, hl##J = 0.f;

// one-time prologue store of pre-scaled bias into LDS (nl==0 lanes only)
#define STB(J)                                                               \
  if (tv##J) {                                                               \
    float b0_ = 0.f, b1_ = 0.f, b2_ = 0.f, b3_ = 0.f;                        \
    if (cell##J < Hn) {                                                      \
      b0_ = biasL[cell##J] * KS1f;                                           \
      b1_ = biasL[Hn + cell##J] * KS1f;                                      \
      b2_ = biasL[2 * Hn + cell##J] * KS2f;                                  \
      b3_ = biasL[3 * Hn + cell##J] * KS1f;                                  \
    }                                                                        \
    s_bv[w][J][quad][0] = b0_;                                               \
    s_bv[w][J][quad][1] = b1_;                                               \
    s_bv[w][J][quad][2] = b2_;                                               \
    s_bv[w][J][quad][3] = b3_;                                               \
  }

// term-major passes: A = FH*uh, B = FL*uh, C = FH*ul
#define MFA(J, FI) if (tv##J) ac##J = MF(FH##FI, uh_, ac##J);
#define MFB(J, FI) if (tv##J) ac##J = MF(FL##FI, uh_, ac##J);
#define MFC(J, FI) if (tv##J) ac##J = MF(FH##FI, ul_, ac##J);

// LC = chunk offset within the source plane (0 or 1); CI = combined chunk idx
// tile J=4's fragments come from LDS (only waves wl==0 of L1/L2 have tv4)
#define MCH5(PH, PL, LC, CI, F0, F1, F2, F3)                                 \
  {                                                                          \
    const short8 uh_ = *(const short8*)&PH[rb][nl][32 * (LC) + quad * 8];    \
    const short8 ul_ = *(const short8*)&PL[rb][nl][32 * (LC) + quad * 8];    \
    short8 f4h_ = {0, 0, 0, 0, 0, 0, 0, 0};                                  \
    short8 f4l_ = {0, 0, 0, 0, 0, 0, 0, 0};                                  \
    if (tv4) {                                                               \
      f4h_ = s_f4[wz2][CI][0][lane];                                         \
      f4l_ = s_f4[wz2][CI][1][lane];                                         \
    }                                                                        \
    MFA(0, F0) MFA(1, F1) MFA(2, F2) MFA(3, F3)                              \
    if (tv4) ac4 = MF(f4h_, uh_, ac4);                                       \
    MFB(0, F0) MFB(1, F1) MFB(2, F2) MFB(3, F3)                              \
    if (tv4) ac4 = MF(f4l_, uh_, ac4);                                       \
    MFC(0, F0) MFC(1, F1) MFC(2, F2) MFC(3, F3)                              \
    if (tv4) ac4 = MF(f4h_, ul_, ac4);                                       \
  }

#define MCH7(LC, F0, F1, F2, F3, F4, F5, F6)                                 \
  {                                                                          \
    const short8 uh_ = *(const short8*)&p1h[rb][nl][32 * (LC) + quad * 8];   \
    const short8 ul_ = *(const short8*)&p1l[rb][nl][32 * (LC) + quad * 8];   \
    MFA(0, F0) MFA(1, F1) MFA(2, F2) MFA(3, F3) MFA(4, F4) MFA(5, F5)        \
    MFA(6, F6)                                                               \
    MFB(0, F0) MFB(1, F1) MFB(2, F2) MFB(3, F3) MFB(4, F4) MFB(5, F5)        \
    MFB(6, F6)                                                               \
    MFC(0, F0) MFC(1, F1) MFC(2, F2) MFC(3, F3) MFC(4, F4) MFC(5, F5)        \
    MFC(6, F6)                                                               \
  }

// cell update for tile J; SINGLE h write into plane (PH,PL) at k = KO+cell
// gates arrive pre-scaled: sigmoid = rcp(1+exp2(z')), tanh = 2*rcp(1+e)-1
#define CUP(J, PH, PL, KO)                                                   \
  if (tv##J) {                                                               \
    const float I_ = rcpa(1.0f + fexp2(ac##J[0]));                           \
    const float F_ = rcpa(1.0f + fexp2(ac##J[1]));                           \
    const float G_ = fmaf(2.0f, rcpa(1.0f + fexp2(ac##J[2])), -1.0f);        \
    const float O_ = rcpa(1.0f + fexp2(ac##J[3]));                           \
    cs##J = fmaf(F_, cs##J, I_ * G_);                                        \
    const float tc_ = fmaf(2.0f, rcpa(1.0f + fexp2(cs##J * KS2f)), -1.0f);   \
    const float hv = O_ * tc_;                                               \
    hl##J = hv;                                                              \
    if (cell##J < Hn)                                                        \
      wsplit(&PH[wb][nl][(KO) + cell##J], &PL[wb][nl][(KO) + cell##J], hv);  \
  }

__global__ __launch_bounds__(512, 1) void lstm_fused(
    const float* __restrict__ xg,    // [B][T]
    const float* __restrict__ wih1, const float* __restrict__ whh1,
    const float* __restrict__ b1, const float* __restrict__ wih2,
    const float* __restrict__ whh2, const float* __restrict__ b2,
    const float* __restrict__ wih3, const float* __restrict__ whh3,
    const float* __restrict__ b3, const float* __restrict__ wfc,
    const float* __restrict__ bfc, float* __restrict__ out)  // [B]
{
  __shared__ __align__(16) short p1h[2][16][SW];  // [x | h1(1..50)]
  __shared__ __align__(16) short p1l[2][16][SW];
  __shared__ __align__(16) short p2h[2][16][SW];  // [h2(0..49)]
  __shared__ __align__(16) short p2l[2][16][SW];
  __shared__ __align__(16) short p3h[2][16][SW];  // [h3(0..49)]
  __shared__ __align__(16) short p3l[2][16][SW];
  __shared__ __align__(16) float s_bv[8][7][4][4];  // pre-scaled bias / wave,tile,quad
  __shared__ __align__(16) short8 s_f4[2][4][2][64];  // tile-4 frags: [L-1][chunk][H/L][lane]
  __shared__ float s_fc[3][16];

  const int tid = threadIdx.x;
  const int w = tid >> 6;
  const int lane = tid & 63;
  const int quad = lane >> 4;
  const int nl = lane & 15;
  const int L = (w < 2) ? 0 : (w < 5) ? 1 : 2;
  const int wl = w - (L == 0 ? 0 : (L == 1 ? 2 : 5));
  const int wz2 = (L == 2) ? 1 : 0;
  const int eb = blockIdx.x * 16;

  const float* wihL = (L == 0) ? wih1 : (L == 1) ? wih2 : wih3;
  const float* whhL = (L == 0) ? whh1 : (L == 1) ? whh2 : whh3;
  const float* biasL = (L == 0) ? b1 : (L == 1) ? b2 : b3;

  LW(0) LW(1) LW(2) LW(3) LW(4) LW(5) LW(6) LW(7) LW(8) LW(9)
  LW(10) LW(11) LW(12) LW(13) LW(14) LW(15) LW(16) LW(17) LW(18) LW(19)

  // park tile-4 fragments in LDS; their registers die here (read in MCH5)
  if (L > 0 && wl == 0) {
    s_f4[wz2][0][0][lane] = FH16; s_f4[wz2][0][1][lane] = FL16;
    s_f4[wz2][1][0][lane] = FH17; s_f4[wz2][1][1][lane] = FL17;
    s_f4[wz2][2][0][lane] = FH18; s_f4[wz2][2][1][lane] = FL18;
    s_f4[wz2][3][0][lane] = FH19; s_f4[wz2][3][1][lane] = FL19;
  }

  BINIT(0) BINIT(1) BINIT(2) BINIT(3) BINIT(4) BINIT(5) BINIT(6)

  for (int i = tid; i < 2 * 16 * SW; i += 512) {
    (&p1h[0][0][0])[i] = 0;
    (&p1l[0][0][0])[i] = 0;
    (&p2h[0][0][0])[i] = 0;
    (&p2l[0][0][0])[i] = 0;
    (&p3h[0][0][0])[i] = 0;
    (&p3l[0][0][0])[i] = 0;
  }
  for (int i = tid; i < 8 * 7 * 4 * 4; i += 512) (&s_bv[0][0][0][0])[i] = 0.f;
  __syncthreads();
  if (w == 0 && lane < 16) {
    const float xv = xg[(size_t)(eb + lane) * Tn + 0];
    wsplit(&p1h[0][lane][0], &p1l[0][lane][0], xv);
  }
  if (nl == 0) {
    STB(0) STB(1) STB(2) STB(3) STB(4) STB(5) STB(6)
  }
  __syncthreads();

#pragma unroll 1
  for (int i = 0; i < Tn + 2; ++i) {
    const int rb = i & 1, wb = rb ^ 1;
    if (L == 0) {
      if (i < Tn) {
        float xv = 0.f;
        if (w == 0 && lane < 16 && i + 1 < Tn)
          xv = xg[(size_t)(eb + lane) * Tn + (i + 1)];
        f32x4 ac0 = *(const f32x4*)s_bv[w][0][quad];
        f32x4 ac1 = *(const f32x4*)s_bv[w][1][quad];
        f32x4 ac2 = *(const f32x4*)s_bv[w][2][quad];
        f32x4 ac3 = *(const f32x4*)s_bv[w][3][quad];
        f32x4 ac4 = *(const f32x4*)s_bv[w][4][quad];
        f32x4 ac5 = *(const f32x4*)s_bv[w][5][quad];
        f32x4 ac6 = *(const f32x4*)s_bv[w][6][quad];
        MCH7(0, 0, 2, 4, 6, 8, 10, 12)
        MCH7(1, 1, 3, 5, 7, 9, 11, 13)
        CUP(0, p1h, p1l, 1)
        CUP(1, p1h, p1l, 1)
        CUP(2, p1h, p1l, 1)
        CUP(3, p1h, p1l, 1)
        CUP(4, p1h, p1l, 1)
        CUP(5, p1h, p1l, 1)
        CUP(6, p1h, p1l, 1)
        if (w == 0 && lane < 16)
          wsplit(&p1h[wb][lane][0], &p1l[wb][lane][0], xv);
      }
    } else if (L == 1) {
      if (i >= 1 && i <= Tn) {
        f32x4 ac0 = *(const f32x4*)s_bv[w][0][quad];
        f32x4 ac1 = *(const f32x4*)s_bv[w][1][quad];
        f32x4 ac2 = *(const f32x4*)s_bv[w][2][quad];
        f32x4 ac3 = *(const f32x4*)s_bv[w][3][quad];
        f32x4 ac4 = *(const f32x4*)s_bv[w][4][quad];
        MCH5(p1h, p1l, 0, 0, 0, 4, 8, 12)    // combined k 0..31  (h1)
        MCH5(p1h, p1l, 1, 1, 1, 5, 9, 13)    // combined k 32..63 (h1)
        MCH5(p2h, p2l, 0, 2, 2, 6, 10, 14)   // combined k 64..95 (h2)
        MCH5(p2h, p2l, 1, 3, 3, 7, 11, 15)   // combined k 96..127(h2)
        CUP(0, p2h, p2l, 0)
        CUP(1, p2h, p2l, 0)
        CUP(2, p2h, p2l, 0)
        CUP(3, p2h, p2l, 0)
        CUP(4, p2h, p2l, 0)
      }
    } else {
      if (i >= 2) {
        f32x4 ac0 = *(const f32x4*)s_bv[w][0][quad];
        f32x4 ac1 = *(const f32x4*)s_bv[w][1][quad];
        f32x4 ac2 = *(const f32x4*)s_bv[w][2][quad];
        f32x4 ac3 = *(const f32x4*)s_bv[w][3][quad];
        f32x4 ac4 = *(const f32x4*)s_bv[w][4][quad];
        MCH5(p2h, p2l, 0, 0, 0, 4, 8, 12)    // h2
        MCH5(p2h, p2l, 1, 1, 1, 5, 9, 13)
        MCH5(p3h, p3l, 0, 2, 2, 6, 10, 14)   // h3
        MCH5(p3h, p3l, 1, 3, 3, 7, 11, 15)
        CUP(0, p3h, p3l, 0)
        CUP(1, p3h, p3l, 0)
        CUP(2, p3h, p3l, 0)
        CUP(3, p3h, p3l, 0)
        CUP(4, p3h, p3l, 0)
      }
    }
    __syncthreads();
  }

  if (L == 2) {
    float pfc = 0.f;
    if (tv0 && cell0 < Hn) pfc += hl0 * wfc[cell0];
    if (tv1 && cell1 < Hn) pfc += hl1 * wfc[cell1];
    if (tv2 && cell2 < Hn) pfc += hl2 * wfc[cell2];
    if (tv3 && cell3 < Hn) pfc += hl3 * wfc[cell3];
    if (tv4 && cell4 < Hn) pfc += hl4 * wfc[cell4];
    pfc += __shfl_xor(pfc, 16);  // sum over quads (cells)
    pfc += __shfl_xor(pfc, 32);
    if (lane < 16) s_fc[wl][lane] = pfc;
  }
  __syncthreads();
  if (tid < 16)
    out[eb + tid] = bfc[0] + s_fc[0][tid] + s_fc[1][tid] + s_fc[2][tid];
}

}  // namespace

extern "C" void kernel_launch(void* const* d_in, const int* in_sizes, int n_in,
                              void* d_out, int out_size, void* d_ws, size_t ws_size,
                              hipStream_t stream) {
  const float* x    = (const float*)d_in[0];
  const float* wih1 = (const float*)d_in[1];
  const float* whh1 = (const float*)d_in[2];
  const float* b1   = (const float*)d_in[3];
  const float* wih2 = (const float*)d_in[4];
  const float* whh2 = (const float*)d_in[5];
  const float* b2   = (const float*)d_in[6];
  const float* wih3 = (const float*)d_in[7];
  const float* whh3 = (const float*)d_in[8];
  const float* b3   = (const float*)d_in[9];
  const float* wfc  = (const float*)d_in[10];
  const float* bfc  = (const float*)d_in[11];
  float* out = (float*)d_out;

  lstm_fused<<<dim3(Bn / 16), dim3(512), 0, stream>>>(
      x, wih1, whh1, b1, wih2, whh2, b2, wih3, whh3, b3, wfc, bfc, out);
}

// Round 7
// 1088.356 us; speedup vs baseline: 1.1200x; 1.0693x over previous
//
#include <hip/hip_runtime.h>
#include <math.h>

namespace {

constexpr int Hn = 50;    // hidden size
constexpr int Bn = 2048;  // batch
constexpr int Tn = 512;   // sequence length
constexpr int SW = 72;    // plane row stride in shorts (144 B)

constexpr float KS1f = -1.44269504088896340736f;  // -log2(e)   (sigmoid rows i,f,o)
constexpr float KS2f = -2.88539008177792681472f;  // -2*log2(e) (tanh row g, and tanh(c))

typedef short short8 __attribute__((ext_vector_type(8)));
typedef float f32x4 __attribute__((ext_vector_type(4)));

__device__ __forceinline__ unsigned bcu(float f) { return __builtin_bit_cast(unsigned, f); }
__device__ __forceinline__ float bcf(unsigned u) { return __builtin_bit_cast(float, u); }
__device__ __forceinline__ float rcpa(float x) { return __builtin_amdgcn_rcpf(x); }

__device__ __forceinline__ float fexp2(float x) {
#if defined(__has_builtin)
#if __has_builtin(__builtin_amdgcn_exp2f)
  return __builtin_amdgcn_exp2f(x);
#else
  return exp2f(x);
#endif
#else
  return exp2f(x);
#endif
}

__device__ __forceinline__ void wsplit(short* ph, short* pl, float v) {
  const unsigned u = bcu(v);
  *ph = (short)(u >> 16);
  *pl = (short)(bcu(v - bcf(u & 0xFFFF0000u)) >> 16);
}

#define MF(a, b, c) __builtin_amdgcn_mfma_f32_16x16x32_bf16(a, b, c, 0, 0, 0)

// ============================================================================
// FUSED 3-layer LSTM + FC, systolic in time.
// R14: 128 blocks x 1024 thr (16 waves = l1:4, l2:6, l3:6) = 4 waves/SIMD.
//  - R13 refuted term-major (951->1147 at equal reg budget): back-to-back
//    dependent MFMAs on one acc are FREE (MAI pipe forwards the accumulator);
//    reverted to R11's tile-major triplets.
//  - R11's residual: 4440 cy/iter vs ~1800 cy issue work = ~60% exposed
//    latency (LDS round-trips, trans chains, barrier skew) with only
//    2 waves/SIMD. Fix: split tiles 2x finer across 2x waves ->
//    4 waves/SIMD. Per-wave: L1 <=4 tiles (tile=wl+4J, J<4, 2 chunks),
//    L2/L3 <=3 tiles (tile=wl+6J, J<3, 4 chunks); tile 12 stays
//    LDS-resident (s_f4) for the wl==0 waves -> per-wave weights 64 VGPR,
//    total ~110 < 128 cap (4 waves/SIMD). Spill tripwire: WRITE_SIZE.
// Kept: biases in LDS (s_bv); exp2-prescaled weights/biases (sigmoid rows
// * -log2e, tanh rows * -2log2e) -> gates rcp(1+exp2(z')); tanh=2*rcp(1+e)-1;
// 3-term split-bf16 (Wh*Uh + Wl*Uh + Wh*Ul); planes K=64: P1=[x,h1(1..50)],
// P2=[h2], P3=[h3]; l2 consumes {P1,P2}, l3 {P2,P3}; ONE barrier/iter.
// ============================================================================

// reg tiles: L1 FI0..7: tile=wl+4*(FI>>1), chunk=FI&1
//            L2/3 FI0..7: tile=wl+6*(FI>>2), chunk=FI&3
// LDS tile:  FI16..19: tile=12 (L>0), chunk=FI&3
#define LW(FI)                                                               \
  short8 FH##FI = {0, 0, 0, 0, 0, 0, 0, 0};                                  \
  short8 FL##FI = {0, 0, 0, 0, 0, 0, 0, 0};                                  \
  {                                                                          \
    const int tile_ = ((FI) >= 16) ? ((L == 0) ? 13 : 12)                    \
                      : (L == 0) ? (wl + 4 * ((FI) >> 1))                    \
                                 : (wl + 6 * ((FI) >> 2));                   \
    const int chunk_ = ((FI) >= 16) ? ((FI)&3)                               \
                       : (L == 0)   ? ((FI)&1)                               \
                                    : ((FI)&3);                              \
    const int cb_ = 4 * tile_ + (nl >> 2);                                   \
    if (tile_ < 13 && cb_ < Hn) {                                            \
      const int row_ = (nl & 3) * Hn + cb_;                                  \
      const float sc_ = ((nl & 3) == 2) ? KS2f : KS1f;                       \
      _Pragma("unroll") for (int jj = 0; jj < 8; ++jj) {                     \
        const int k_ = 32 * chunk_ + quad * 8 + jj;                          \
        float wv = 0.f;                                                      \
        if (L == 0) {                                                        \
          if (k_ == 0) wv = wihL[row_];                                      \
          else if (k_ <= Hn) wv = whhL[row_ * Hn + k_ - 1];                  \
        } else if (L == 1) {                                                 \
          if (k_ >= 1 && k_ <= Hn) wv = wihL[row_ * Hn + k_ - 1];            \
          else if (k_ >= 64 && k_ < 64 + Hn) wv = whhL[row_ * Hn + k_ - 64]; \
        } else {                                                             \
          if (k_ < Hn) wv = wihL[row_ * Hn + k_];                            \
          else if (k_ >= 64 && k_ < 64 + Hn) wv = whhL[row_ * Hn + k_ - 64]; \
        }                                                                    \
        wv *= sc_;                                                           \
        const unsigned uu = bcu(wv);                                         \
        FH##FI[jj] = (short)(uu >> 16);                                      \
        FL##FI[jj] = (short)(bcu(wv - bcf(uu & 0xFFFF0000u)) >> 16);         \
      }                                                                      \
    }                                                                        \
  }

#define BINIT(J)                                                             \
  const int tile##J =                                                        \
      (L == 0) ? (wl + 4 * (J)) : ((J) < 3 ? (wl + 6 * (J)) : 13);           \
  const int tv##J = tile##J < 13;                                            \
  const int cell##J = 4 * tile##J + quad;                                    \
  float cs##J = 0.f, hl##J = 0.f;

// one-time prologue store of pre-scaled bias into LDS (nl==0 lanes only)
#define STB(J)                                                               \
  if (tv##J) {                                                               \
    float b0_ = 0.f, b1_ = 0.f, b2_ = 0.f, b3_ = 0.f;                        \
    if (cell##J < Hn) {                                                      \
      b0_ = biasL[cell##J] * KS1f;                                           \
      b1_ = biasL[Hn + cell##J] * KS1f;                                      \
      b2_ = biasL[2 * Hn + cell##J] * KS2f;                                  \
      b3_ = biasL[3 * Hn + cell##J] * KS1f;                                  \
    }                                                                        \
    s_bv[w][J][quad][0] = b0_;                                               \
    s_bv[w][J][quad][1] = b1_;                                               \
    s_bv[w][J][quad][2] = b2_;                                               \
    s_bv[w][J][quad][3] = b3_;                                               \
  }

// tile-major triplet (R11-proven: dependent same-acc MFMAs are free)
#define MTM(J, FI)                                                           \
  if (tv##J) {                                                               \
    ac##J = MF(FH##FI, uh_, ac##J);                                          \
    ac##J = MF(FL##FI, uh_, ac##J);                                          \
    ac##J = MF(FH##FI, ul_, ac##J);                                          \
  }

// tile 12 (J=2) fragments from LDS (only wl==0 waves of L2/L3 have tv2)
#define MTMS(CI)                                                             \
  if (tv2) {                                                                 \
    const short8 fh_ = s_f4[wz2][CI][0][lane];                               \
    const short8 fl_ = s_f4[wz2][CI][1][lane];                               \
    ac2 = MF(fh_, uh_, ac2);                                                 \
    ac2 = MF(fl_, uh_, ac2);                                                 \
    ac2 = MF(fh_, ul_, ac2);                                                 \
  }

#define MCH_L1(LC, F0, F1, F2, F3)                                           \
  {                                                                          \
    const short8 uh_ = *(const short8*)&p1h[rb][nl][32 * (LC) + quad * 8];   \
    const short8 ul_ = *(const short8*)&p1l[rb][nl][32 * (LC) + quad * 8];   \
    MTM(0, F0) MTM(1, F1) MTM(2, F2) MTM(3, F3)                              \
  }

#define MCH_L23(PH, PL, LC, CI, F0, F1)                                      \
  {                                                                          \
    const short8 uh_ = *(const short8*)&PH[rb][nl][32 * (LC) + quad * 8];    \
    const short8 ul_ = *(const short8*)&PL[rb][nl][32 * (LC) + quad * 8];    \
    MTM(0, F0) MTM(1, F1) MTMS(CI)                                           \
  }

// cell update for tile J; SINGLE h write into plane (PH,PL) at k = KO+cell
#define CUP(J, PH, PL, KO)                                                   \
  if (tv##J) {                                                               \
    const float I_ = rcpa(1.0f + fexp2(ac##J[0]));                           \
    const float F_ = rcpa(1.0f + fexp2(ac##J[1]));                           \
    const float G_ = fmaf(2.0f, rcpa(1.0f + fexp2(ac##J[2])), -1.0f);        \
    const float O_ = rcpa(1.0f + fexp2(ac##J[3]));                           \
    cs##J = fmaf(F_, cs##J, I_ * G_);                                        \
    const float tc_ = fmaf(2.0f, rcpa(1.0f + fexp2(cs##J * KS2f)), -1.0f);   \
    const float hv = O_ * tc_;                                               \
    hl##J = hv;                                                              \
    if (cell##J < Hn)                                                        \
      wsplit(&PH[wb][nl][(KO) + cell##J], &PL[wb][nl][(KO) + cell##J], hv);  \
  }

__global__ __launch_bounds__(1024, 4) void lstm_fused(
    const float* __restrict__ xg,    // [B][T]
    const float* __restrict__ wih1, const float* __restrict__ whh1,
    const float* __restrict__ b1, const float* __restrict__ wih2,
    const float* __restrict__ whh2, const float* __restrict__ b2,
    const float* __restrict__ wih3, const float* __restrict__ whh3,
    const float* __restrict__ b3, const float* __restrict__ wfc,
    const float* __restrict__ bfc, float* __restrict__ out)  // [B]
{
  __shared__ __align__(16) short p1h[2][16][SW];  // [x | h1(1..50)]
  __shared__ __align__(16) short p1l[2][16][SW];
  __shared__ __align__(16) short p2h[2][16][SW];  // [h2(0..49)]
  __shared__ __align__(16) short p2l[2][16][SW];
  __shared__ __align__(16) short p3h[2][16][SW];  // [h3(0..49)]
  __shared__ __align__(16) short p3l[2][16][SW];
  __shared__ __align__(16) float s_bv[16][4][4][4];  // pre-scaled bias / wave,tile,quad
  __shared__ __align__(16) short8 s_f4[2][4][2][64]; // tile-12 frags: [L-1][chunk][H/L][lane]
  __shared__ float s_fc[6][16];

  const int tid = threadIdx.x;
  const int w = tid >> 6;
  const int lane = tid & 63;
  const int quad = lane >> 4;
  const int nl = lane & 15;
  const int L = (w < 4) ? 0 : (w < 10) ? 1 : 2;
  const int wl = w - (L == 0 ? 0 : (L == 1 ? 4 : 10));
  const int wz2 = (L == 2) ? 1 : 0;
  const int eb = blockIdx.x * 16;

  const float* wihL = (L == 0) ? wih1 : (L == 1) ? wih2 : wih3;
  const float* whhL = (L == 0) ? whh1 : (L == 1) ? whh2 : whh3;
  const float* biasL = (L == 0) ? b1 : (L == 1) ? b2 : b3;

  LW(0) LW(1) LW(2) LW(3) LW(4) LW(5) LW(6) LW(7)
  LW(16) LW(17) LW(18) LW(19)

  // park tile-12 fragments in LDS; their registers die here
  if (L > 0 && wl == 0) {
    s_f4[wz2][0][0][lane] = FH16; s_f4[wz2][0][1][lane] = FL16;
    s_f4[wz2][1][0][lane] = FH17; s_f4[wz2][1][1][lane] = FL17;
    s_f4[wz2][2][0][lane] = FH18; s_f4[wz2][2][1][lane] = FL18;
    s_f4[wz2][3][0][lane] = FH19; s_f4[wz2][3][1][lane] = FL19;
  }

  BINIT(0) BINIT(1) BINIT(2) BINIT(3)

  for (int i = tid; i < 2 * 16 * SW; i += 1024) {
    (&p1h[0][0][0])[i] = 0;
    (&p1l[0][0][0])[i] = 0;
    (&p2h[0][0][0])[i] = 0;
    (&p2l[0][0][0])[i] = 0;
    (&p3h[0][0][0])[i] = 0;
    (&p3l[0][0][0])[i] = 0;
  }
  for (int i = tid; i < 16 * 4 * 4 * 4; i += 1024) (&s_bv[0][0][0][0])[i] = 0.f;
  __syncthreads();
  if (w == 0 && lane < 16) {
    const float xv = xg[(size_t)(eb + lane) * Tn + 0];
    wsplit(&p1h[0][lane][0], &p1l[0][lane][0], xv);
  }
  if (nl == 0) {
    STB(0) STB(1) STB(2) STB(3)
  }
  __syncthreads();

#pragma unroll 1
  for (int i = 0; i < Tn + 2; ++i) {
    const int rb = i & 1, wb = rb ^ 1;
    if (L == 0) {
      if (i < Tn) {
        float xv = 0.f;
        if (w == 0 && lane < 16 && i + 1 < Tn)
          xv = xg[(size_t)(eb + lane) * Tn + (i + 1)];
        f32x4 ac0 = *(const f32x4*)s_bv[w][0][quad];
        f32x4 ac1 = *(const f32x4*)s_bv[w][1][quad];
        f32x4 ac2 = *(const f32x4*)s_bv[w][2][quad];
        f32x4 ac3 = *(const f32x4*)s_bv[w][3][quad];
        MCH_L1(0, 0, 2, 4, 6)
        MCH_L1(1, 1, 3, 5, 7)
        CUP(0, p1h, p1l, 1)
        CUP(1, p1h, p1l, 1)
        CUP(2, p1h, p1l, 1)
        CUP(3, p1h, p1l, 1)
        if (w == 0 && lane < 16)
          wsplit(&p1h[wb][lane][0], &p1l[wb][lane][0], xv);
      }
    } else if (L == 1) {
      if (i >= 1 && i <= Tn) {
        f32x4 ac0 = *(const f32x4*)s_bv[w][0][quad];
        f32x4 ac1 = *(const f32x4*)s_bv[w][1][quad];
        f32x4 ac2 = *(const f32x4*)s_bv[w][2][quad];
        MCH_L23(p1h, p1l, 0, 0, 0, 4)   // combined k 0..31  (h1)
        MCH_L23(p1h, p1l, 1, 1, 1, 5)   // combined k 32..63 (h1)
        MCH_L23(p2h, p2l, 0, 2, 2, 6)   // combined k 64..95 (h2)
        MCH_L23(p2h, p2l, 1, 3, 3, 7)   // combined k 96..127(h2)
        CUP(0, p2h, p2l, 0)
        CUP(1, p2h, p2l, 0)
        CUP(2, p2h, p2l, 0)
      }
    } else {
      if (i >= 2) {
        f32x4 ac0 = *(const f32x4*)s_bv[w][0][quad];
        f32x4 ac1 = *(const f32x4*)s_bv[w][1][quad];
        f32x4 ac2 = *(const f32x4*)s_bv[w][2][quad];
        MCH_L23(p2h, p2l, 0, 0, 0, 4)   // h2
        MCH_L23(p2h, p2l, 1, 1, 1, 5)
        MCH_L23(p3h, p3l, 0, 2, 2, 6)   // h3
        MCH_L23(p3h, p3l, 1, 3, 3, 7)
        CUP(0, p3h, p3l, 0)
        CUP(1, p3h, p3l, 0)
        CUP(2, p3h, p3l, 0)
      }
    }
    __syncthreads();
  }

  if (L == 2) {
    float pfc = 0.f;
    if (tv0 && cell0 < Hn) pfc += hl0 * wfc[cell0];
    if (tv1 && cell1 < Hn) pfc += hl1 * wfc[cell1];
    if (tv2 && cell2 < Hn) pfc += hl2 * wfc[cell2];
    pfc += __shfl_xor(pfc, 16);  // sum over quads (cells)
    pfc += __shfl_xor(pfc, 32);
    if (lane < 16) s_fc[wl][lane] = pfc;
  }
  __syncthreads();
  if (tid < 16)
    out[eb + tid] = bfc[0] + s_fc[0][tid] + s_fc[1][tid] + s_fc[2][tid] +
                    s_fc[3][tid] + s_fc[4][tid] + s_fc[5][tid];
}

}  // namespace

extern "C" void kernel_launch(void* const* d_in, const int* in_sizes, int n_in,
                              void* d_out, int out_size, void* d_ws, size_t ws_size,
                              hipStream_t stream) {
  const float* x    = (const float*)d_in[0];
  const float* wih1 = (const float*)d_in[1];
  const float* whh1 = (const float*)d_in[2];
  const float* b1   = (const float*)d_in[3];
  const float* wih2 = (const float*)d_in[4];
  const float* whh2 = (const float*)d_in[5];
  const float* b2   = (const float*)d_in[6];
  const float* wih3 = (const float*)d_in[7];
  const float* whh3 = (const float*)d_in[8];
  const float* b3   = (const float*)d_in[9];
  const float* wfc  = (const float*)d_in[10];
  const float* bfc  = (const float*)d_in[11];
  float* out = (float*)d_out;

  lstm_fused<<<dim3(Bn / 16), dim3(1024), 0, stream>>>(
      x, wih1, whh1, b1, wih2, whh2, b2, wih3, whh3, b3, wfc, bfc, out);
}

// Round 8
// 936.891 us; speedup vs baseline: 1.3011x; 1.1617x over previous
//
#include <hip/hip_runtime.h>
#include <math.h>

namespace {

constexpr int Hn = 50;    // hidden size
constexpr int Bn = 2048;  // batch
constexpr int Tn = 512;   // sequence length
constexpr int SW = 72;    // plane row stride in shorts (144 B)

constexpr float KS1f = -1.44269504088896340736f;  // -log2(e)   (sigmoid rows i,f,o)
constexpr float KS2f = -2.88539008177792681472f;  // -2*log2(e) (tanh row g, and tanh(c))

typedef short short8 __attribute__((ext_vector_type(8)));
typedef float f32x4 __attribute__((ext_vector_type(4)));

__device__ __forceinline__ unsigned bcu(float f) { return __builtin_bit_cast(unsigned, f); }
__device__ __forceinline__ float bcf(unsigned u) { return __builtin_bit_cast(float, u); }
__device__ __forceinline__ float rcpa(float x) { return __builtin_amdgcn_rcpf(x); }

__device__ __forceinline__ float fexp2(float x) {
#if defined(__has_builtin)
#if __has_builtin(__builtin_amdgcn_exp2f)
  return __builtin_amdgcn_exp2f(x);
#else
  return exp2f(x);
#endif
#else
  return exp2f(x);
#endif
}

__device__ __forceinline__ void wsplit(short* ph, short* pl, float v) {
  const unsigned u = bcu(v);
  *ph = (short)(u >> 16);
  *pl = (short)(bcu(v - bcf(u & 0xFFFF0000u)) >> 16);
}

#define MF(a, b, c) __builtin_amdgcn_mfma_f32_16x16x32_bf16(a, b, c, 0, 0, 0)

// ============================================================================
// FUSED 3-layer LSTM + FC, systolic in time.
// R15: 128 blocks x 768 thr (12 waves = l1:4, l2:4, l3:4) = 3 waves/SIMD,
// register cap 512/3 = 170 unified.
//  - R14 post-mortem: 1024-thr/(1024,4) forced a 128 unified cap which the
//    compiler split 64 arch + 64 acc -> 18 dwords/thread spilled (WRITE_SIZE
//    9224 KB). TLP idea untested; spills ate it. R13 refuted term-major
//    (dependent same-acc MFMAs are free); tile-major triplets kept.
//  - R15 budget: tiles = wl+4J (J<4; 16 slots, 13 used; tile 12 only wl==0).
//    L1 waves: all 4 tiles in regs (2 chunks -> 64 VGPR). L2/3 waves: J0,J1
//    in regs (4 chunks -> 64 VGPR); J2 (tiles 8..11) and J3 (tile 12) parked
//    in LDS at prologue (s_f4j2 64KB, s_f4j3 16KB), re-read per chunk.
//    Peak ~130 < 170. Spill tripwire: WRITE_SIZE.
//  - Balance: every wave <=4 CUPs (R11 L1 had 7) -> tighter barrier skew.
// Kept: biases in LDS (s_bv); exp2-prescaled weights/biases (sigmoid rows
// * -log2e, tanh rows * -2log2e) -> gates rcp(1+exp2(z')); tanh=2*rcp(1+e)-1;
// 3-term split-bf16 (Wh*Uh + Wl*Uh + Wh*Ul); planes K=64: P1=[x,h1(1..50)],
// P2=[h2], P3=[h3]; l2 consumes {P1,P2}, l3 {P2,P3}; ONE barrier/iter.
// ============================================================================

// reg tiles:  L1 FI0..7: tile=wl+4*(FI>>1), chunk=FI&1
//             L2/3 FI0..7: tile=wl+4*(FI>>2) (J0,J1), chunk=FI&3
// LDS tiles (L>0 only): FI8..11: tile=wl+8 (J2), chunk=FI&3
//                       FI16..19: tile=12 (wl==0 only), chunk=FI&3
#define LW(FI)                                                               \
  short8 FH##FI = {0, 0, 0, 0, 0, 0, 0, 0};                                  \
  short8 FL##FI = {0, 0, 0, 0, 0, 0, 0, 0};                                  \
  {                                                                          \
    const int tile_ =                                                        \
        ((FI) >= 16) ? ((L == 0 || wl != 0) ? 13 : 12)                       \
        : ((FI) >= 8) ? ((L == 0) ? 13 : (wl + 8))                           \
        : (L == 0)    ? (wl + 4 * ((FI) >> 1))                               \
                      : (wl + 4 * ((FI) >> 2));                              \
    const int chunk_ = ((FI) >= 8) ? ((FI)&3)                                \
                       : (L == 0)  ? ((FI)&1)                                \
                                   : ((FI)&3);                               \
    const int cb_ = 4 * tile_ + (nl >> 2);                                   \
    if (tile_ < 13 && cb_ < Hn) {                                            \
      const int row_ = (nl & 3) * Hn + cb_;                                  \
      const float sc_ = ((nl & 3) == 2) ? KS2f : KS1f;                       \
      _Pragma("unroll") for (int jj = 0; jj < 8; ++jj) {                     \
        const int k_ = 32 * chunk_ + quad * 8 + jj;                          \
        float wv = 0.f;                                                      \
        if (L == 0) {                                                        \
          if (k_ == 0) wv = wihL[row_];                                      \
          else if (k_ <= Hn) wv = whhL[row_ * Hn + k_ - 1];                  \
        } else if (L == 1) {                                                 \
          if (k_ >= 1 && k_ <= Hn) wv = wihL[row_ * Hn + k_ - 1];            \
          else if (k_ >= 64 && k_ < 64 + Hn) wv = whhL[row_ * Hn + k_ - 64]; \
        } else {                                                             \
          if (k_ < Hn) wv = wihL[row_ * Hn + k_];                            \
          else if (k_ >= 64 && k_ < 64 + Hn) wv = whhL[row_ * Hn + k_ - 64]; \
        }                                                                    \
        wv *= sc_;                                                           \
        const unsigned uu = bcu(wv);                                         \
        FH##FI[jj] = (short)(uu >> 16);                                      \
        FL##FI[jj] = (short)(bcu(wv - bcf(uu & 0xFFFF0000u)) >> 16);         \
      }                                                                      \
    }                                                                        \
  }

#define BINIT(J)                                                             \
  const int tile##J = wl + 4 * (J);                                          \
  const int tv##J = tile##J < 13;                                            \
  const int cell##J = 4 * tile##J + quad;                                    \
  float cs##J = 0.f, hl##J = 0.f;

// one-time prologue store of pre-scaled bias into LDS (nl==0 lanes only)
#define STB(J)                                                               \
  if (tv##J) {                                                               \
    float b0_ = 0.f, b1_ = 0.f, b2_ = 0.f, b3_ = 0.f;                        \
    if (cell##J < Hn) {                                                      \
      b0_ = biasL[cell##J] * KS1f;                                           \
      b1_ = biasL[Hn + cell##J] * KS1f;                                      \
      b2_ = biasL[2 * Hn + cell##J] * KS2f;                                  \
      b3_ = biasL[3 * Hn + cell##J] * KS1f;                                  \
    }                                                                        \
    s_bv[w][J][quad][0] = b0_;                                               \
    s_bv[w][J][quad][1] = b1_;                                               \
    s_bv[w][J][quad][2] = b2_;                                               \
    s_bv[w][J][quad][3] = b3_;                                               \
  }

// tile-major triplet (R13-proven: dependent same-acc MFMAs are free)
#define MTM(J, FI)                                                           \
  if (tv##J) {                                                               \
    ac##J = MF(FH##FI, uh_, ac##J);                                          \
    ac##J = MF(FL##FI, uh_, ac##J);                                          \
    ac##J = MF(FH##FI, ul_, ac##J);                                          \
  }

// J2 (tiles 8..11, all L2/3 waves) from LDS
#define MTMS2(CI)                                                            \
  {                                                                          \
    const short8 fh_ = s_f4j2[wz2][wl][CI][0][lane];                         \
    const short8 fl_ = s_f4j2[wz2][wl][CI][1][lane];                         \
    ac2 = MF(fh_, uh_, ac2);                                                 \
    ac2 = MF(fl_, uh_, ac2);                                                 \
    ac2 = MF(fh_, ul_, ac2);                                                 \
  }

// J3 (tile 12, wl==0 waves of L2/3) from LDS
#define MTMS3(CI)                                                            \
  if (tv3) {                                                                 \
    const short8 fh_ = s_f4j3[wz2][CI][0][lane];                             \
    const short8 fl_ = s_f4j3[wz2][CI][1][lane];                             \
    ac3 = MF(fh_, uh_, ac3);                                                 \
    ac3 = MF(fl_, uh_, ac3);                                                 \
    ac3 = MF(fh_, ul_, ac3);                                                 \
  }

#define MCH_L1(LC, F0, F1, F2, F3)                                           \
  {                                                                          \
    const short8 uh_ = *(const short8*)&p1h[rb][nl][32 * (LC) + quad * 8];   \
    const short8 ul_ = *(const short8*)&p1l[rb][nl][32 * (LC) + quad * 8];   \
    MTM(0, F0) MTM(1, F1) MTM(2, F2) MTM(3, F3)                              \
  }

#define MCH_L23(PH, PL, LC, CI, F0, F1)                                      \
  {                                                                          \
    const short8 uh_ = *(const short8*)&PH[rb][nl][32 * (LC) + quad * 8];    \
    const short8 ul_ = *(const short8*)&PL[rb][nl][32 * (LC) + quad * 8];    \
    MTM(0, F0) MTM(1, F1) MTMS2(CI) MTMS3(CI)                                \
  }

// cell update for tile J; SINGLE h write into plane (PH,PL) at k = KO+cell
#define CUP(J, PH, PL, KO)                                                   \
  if (tv##J) {                                                               \
    const float I_ = rcpa(1.0f + fexp2(ac##J[0]));                           \
    const float F_ = rcpa(1.0f + fexp2(ac##J[1]));                           \
    const float G_ = fmaf(2.0f, rcpa(1.0f + fexp2(ac##J[2])), -1.0f);        \
    const float O_ = rcpa(1.0f + fexp2(ac##J[3]));                           \
    cs##J = fmaf(F_, cs##J, I_ * G_);                                        \
    const float tc_ = fmaf(2.0f, rcpa(1.0f + fexp2(cs##J * KS2f)), -1.0f);   \
    const float hv = O_ * tc_;                                               \
    hl##J = hv;                                                              \
    if (cell##J < Hn)                                                        \
      wsplit(&PH[wb][nl][(KO) + cell##J], &PL[wb][nl][(KO) + cell##J], hv);  \
  }

__global__ __launch_bounds__(768, 3) void lstm_fused(
    const float* __restrict__ xg,    // [B][T]
    const float* __restrict__ wih1, const float* __restrict__ whh1,
    const float* __restrict__ b1, const float* __restrict__ wih2,
    const float* __restrict__ whh2, const float* __restrict__ b2,
    const float* __restrict__ wih3, const float* __restrict__ whh3,
    const float* __restrict__ b3, const float* __restrict__ wfc,
    const float* __restrict__ bfc, float* __restrict__ out)  // [B]
{
  __shared__ __align__(16) short p1h[2][16][SW];  // [x | h1(1..50)]
  __shared__ __align__(16) short p1l[2][16][SW];
  __shared__ __align__(16) short p2h[2][16][SW];  // [h2(0..49)]
  __shared__ __align__(16) short p2l[2][16][SW];
  __shared__ __align__(16) short p3h[2][16][SW];  // [h3(0..49)]
  __shared__ __align__(16) short p3l[2][16][SW];
  __shared__ __align__(16) float s_bv[12][4][4][4];    // pre-scaled bias
  __shared__ __align__(16) short8 s_f4j2[2][4][4][2][64];  // J2 frags [L-1][wl][chunk][H/L][lane]
  __shared__ __align__(16) short8 s_f4j3[2][4][2][64];     // J3 (tile12) frags
  __shared__ float s_fc[4][16];

  const int tid = threadIdx.x;
  const int w = tid >> 6;
  const int lane = tid & 63;
  const int quad = lane >> 4;
  const int nl = lane & 15;
  const int L = (w < 4) ? 0 : (w < 8) ? 1 : 2;
  const int wl = w & 3;
  const int wz2 = (L == 2) ? 1 : 0;
  const int eb = blockIdx.x * 16;

  const float* wihL = (L == 0) ? wih1 : (L == 1) ? wih2 : wih3;
  const float* whhL = (L == 0) ? whh1 : (L == 1) ? whh2 : whh3;
  const float* biasL = (L == 0) ? b1 : (L == 1) ? b2 : b3;

  LW(0) LW(1) LW(2) LW(3) LW(4) LW(5) LW(6) LW(7)
  LW(8) LW(9) LW(10) LW(11)
  LW(16) LW(17) LW(18) LW(19)

  // park J2/J3 fragments in LDS; their registers die here
  if (L > 0) {
    s_f4j2[wz2][wl][0][0][lane] = FH8;  s_f4j2[wz2][wl][0][1][lane] = FL8;
    s_f4j2[wz2][wl][1][0][lane] = FH9;  s_f4j2[wz2][wl][1][1][lane] = FL9;
    s_f4j2[wz2][wl][2][0][lane] = FH10; s_f4j2[wz2][wl][2][1][lane] = FL10;
    s_f4j2[wz2][wl][3][0][lane] = FH11; s_f4j2[wz2][wl][3][1][lane] = FL11;
    if (wl == 0) {
      s_f4j3[wz2][0][0][lane] = FH16; s_f4j3[wz2][0][1][lane] = FL16;
      s_f4j3[wz2][1][0][lane] = FH17; s_f4j3[wz2][1][1][lane] = FL17;
      s_f4j3[wz2][2][0][lane] = FH18; s_f4j3[wz2][2][1][lane] = FL18;
      s_f4j3[wz2][3][0][lane] = FH19; s_f4j3[wz2][3][1][lane] = FL19;
    }
  }

  BINIT(0) BINIT(1) BINIT(2) BINIT(3)

  for (int i = tid; i < 2 * 16 * SW; i += 768) {
    (&p1h[0][0][0])[i] = 0;
    (&p1l[0][0][0])[i] = 0;
    (&p2h[0][0][0])[i] = 0;
    (&p2l[0][0][0])[i] = 0;
    (&p3h[0][0][0])[i] = 0;
    (&p3l[0][0][0])[i] = 0;
  }
  for (int i = tid; i < 12 * 4 * 4 * 4; i += 768) (&s_bv[0][0][0][0])[i] = 0.f;
  __syncthreads();
  if (w == 0 && lane < 16) {
    const float xv = xg[(size_t)(eb + lane) * Tn + 0];
    wsplit(&p1h[0][lane][0], &p1l[0][lane][0], xv);
  }
  if (nl == 0) {
    STB(0) STB(1) STB(2) STB(3)
  }
  __syncthreads();

#pragma unroll 1
  for (int i = 0; i < Tn + 2; ++i) {
    const int rb = i & 1, wb = rb ^ 1;
    if (L == 0) {
      if (i < Tn) {
        float xv = 0.f;
        if (w == 0 && lane < 16 && i + 1 < Tn)
          xv = xg[(size_t)(eb + lane) * Tn + (i + 1)];
        f32x4 ac0 = *(const f32x4*)s_bv[w][0][quad];
        f32x4 ac1 = *(const f32x4*)s_bv[w][1][quad];
        f32x4 ac2 = *(const f32x4*)s_bv[w][2][quad];
        f32x4 ac3 = *(const f32x4*)s_bv[w][3][quad];
        MCH_L1(0, 0, 2, 4, 6)
        MCH_L1(1, 1, 3, 5, 7)
        CUP(0, p1h, p1l, 1)
        CUP(1, p1h, p1l, 1)
        CUP(2, p1h, p1l, 1)
        CUP(3, p1h, p1l, 1)
        if (w == 0 && lane < 16)
          wsplit(&p1h[wb][lane][0], &p1l[wb][lane][0], xv);
      }
    } else if (L == 1) {
      if (i >= 1 && i <= Tn) {
        f32x4 ac0 = *(const f32x4*)s_bv[w][0][quad];
        f32x4 ac1 = *(const f32x4*)s_bv[w][1][quad];
        f32x4 ac2 = *(const f32x4*)s_bv[w][2][quad];
        f32x4 ac3 = *(const f32x4*)s_bv[w][3][quad];
        MCH_L23(p1h, p1l, 0, 0, 0, 4)   // combined k 0..31  (h1)
        MCH_L23(p1h, p1l, 1, 1, 1, 5)   // combined k 32..63 (h1)
        MCH_L23(p2h, p2l, 0, 2, 2, 6)   // combined k 64..95 (h2)
        MCH_L23(p2h, p2l, 1, 3, 3, 7)   // combined k 96..127(h2)
        CUP(0, p2h, p2l, 0)
        CUP(1, p2h, p2l, 0)
        CUP(2, p2h, p2l, 0)
        CUP(3, p2h, p2l, 0)
      }
    } else {
      if (i >= 2) {
        f32x4 ac0 = *(const f32x4*)s_bv[w][0][quad];
        f32x4 ac1 = *(const f32x4*)s_bv[w][1][quad];
        f32x4 ac2 = *(const f32x4*)s_bv[w][2][quad];
        f32x4 ac3 = *(const f32x4*)s_bv[w][3][quad];
        MCH_L23(p2h, p2l, 0, 0, 0, 4)   // h2
        MCH_L23(p2h, p2l, 1, 1, 1, 5)
        MCH_L23(p3h, p3l, 0, 2, 2, 6)   // h3
        MCH_L23(p3h, p3l, 1, 3, 3, 7)
        CUP(0, p3h, p3l, 0)
        CUP(1, p3h, p3l, 0)
        CUP(2, p3h, p3l, 0)
        CUP(3, p3h, p3l, 0)
      }
    }
    __syncthreads();
  }

  if (L == 2) {
    float pfc = 0.f;
    if (tv0 && cell0 < Hn) pfc += hl0 * wfc[cell0];
    if (tv1 && cell1 < Hn) pfc += hl1 * wfc[cell1];
    if (tv2 && cell2 < Hn) pfc += hl2 * wfc[cell2];
    if (tv3 && cell3 < Hn) pfc += hl3 * wfc[cell3];
    pfc += __shfl_xor(pfc, 16);  // sum over quads (cells)
    pfc += __shfl_xor(pfc, 32);
    if (lane < 16) s_fc[wl][lane] = pfc;
  }
  __syncthreads();
  if (tid < 16)
    out[eb + tid] = bfc[0] + s_fc[0][tid] + s_fc[1][tid] + s_fc[2][tid] +
                    s_fc[3][tid];
}

}  // namespace

extern "C" void kernel_launch(void* const* d_in, const int* in_sizes, int n_in,
                              void* d_out, int out_size, void* d_ws, size_t ws_size,
                              hipStream_t stream) {
  const float* x    = (const float*)d_in[0];
  const float* wih1 = (const float*)d_in[1];
  const float* whh1 = (const float*)d_in[2];
  const float* b1   = (const float*)d_in[3];
  const float* wih2 = (const float*)d_in[4];
  const float* whh2 = (const float*)d_in[5];
  const float* b2   = (const float*)d_in[6];
  const float* wih3 = (const float*)d_in[7];
  const float* whh3 = (const float*)d_in[8];
  const float* b3   = (const float*)d_in[9];
  const float* wfc  = (const float*)d_in[10];
  const float* bfc  = (const float*)d_in[11];
  float* out = (float*)d_out;

  lstm_fused<<<dim3(Bn / 16), dim3(768), 0, stream>>>(
      x, wih1, whh1, b1, wih2, whh2, b2, wih3, whh3, b3, wfc, bfc, out);
}